// Round 1
// baseline (299.657 us; speedup 1.0000x reference)
//
#include <hip/hip_runtime.h>
#include <hip/hip_bf16.h>
#include <math.h>

#define N_PTS 16384
#define DIM   512
#define BM    128
#define BN    128
#define BK    64
#define NBLK  (N_PTS / BM)   // 128
#define NTRI  (NBLK * (NBLK + 1) / 2)  // 8256

typedef __bf16 bf16x8 __attribute__((ext_vector_type(8)));
typedef float  f32x4  __attribute__((ext_vector_type(4)));

// ---- order-preserving float->uint encode (monotonic for all finite floats)
__device__ __forceinline__ unsigned int ford(float f) {
    unsigned int u = __float_as_uint(f);
    return (u & 0x80000000u) ? ~u : (u | 0x80000000u);
}

// =====================================================================
// Kernel 1: fp32 -> bf16 convert (vectorized 8/thread) + init best[] = 0
// =====================================================================
__global__ void k_convert(const float* __restrict__ x,
                          __bf16* __restrict__ xb,
                          unsigned long long* __restrict__ best) {
    int t = blockIdx.x * blockDim.x + threadIdx.x;   // 0 .. 1048575
    size_t e = (size_t)t * 8;
    float4 f0 = *(const float4*)(x + e);
    float4 f1 = *(const float4*)(x + e + 4);
    bf16x8 v;
    v[0] = (__bf16)f0.x; v[1] = (__bf16)f0.y; v[2] = (__bf16)f0.z; v[3] = (__bf16)f0.w;
    v[4] = (__bf16)f1.x; v[5] = (__bf16)f1.y; v[6] = (__bf16)f1.z; v[7] = (__bf16)f1.w;
    *(bf16x8*)(xb + e) = v;
    if (t < N_PTS) best[t] = 0ull;   // encodes most-negative float, index mask
}

// =====================================================================
// Kernel 2: S = Xb * Xb^T on upper-triangular tiles, fused row/col argmax
// m97 structure: 128x128 tile, BK=64, 4 waves (2x2), 16x16x32 bf16 MFMA,
// global_load_lds width=16, 2 barriers per K-step.
// =====================================================================
__global__ void k_gemm_argmax(const __bf16* __restrict__ xb,
                              unsigned long long* __restrict__ best) {
    __shared__ __bf16 As[BM * BK];
    __shared__ __bf16 Bs[BN * BK];

    // decode blockIdx.x -> (bm <= bn), column-major triangle: t = bn*(bn+1)/2 + bm
    int t = (int)blockIdx.x;
    int bn = (int)((sqrtf(8.0f * (float)t + 1.0f) - 1.0f) * 0.5f);
    while ((bn + 1) * (bn + 2) / 2 <= t) ++bn;
    while (bn * (bn + 1) / 2 > t) --bn;
    int bm = t - bn * (bn + 1) / 2;

    const int tid  = (int)threadIdx.x;
    const int lane = tid & 63;
    const int wave = tid >> 6;       // 0..3
    const int wr   = wave >> 1;      // wave row (0/1) -> 64-row band
    const int wc   = wave & 1;       // wave col (0/1) -> 64-col band
    const int lr   = lane & 15;      // A/B frag row; C frag col
    const int lk   = lane >> 4;      // k-group / C row-group

    f32x4 acc[4][4] = {};            // 4x4 fragments of 16x16 -> 64x64 per wave

    const int arow0 = bm * BM;
    const int brow0 = bn * BN;
    const int ldsbase = tid & ~63;   // wave-uniform chunk base

    for (int kk = 0; kk < DIM; kk += BK) {
        // ---- stage A and B tiles: 128 rows x 64 k, row-major, linear LDS ----
#pragma unroll
        for (int it = 0; it < 4; ++it) {
            int ci  = it * 256 + tid;       // 16B chunk index within tile
            int row = ci >> 3;              // 8 bf16 per chunk, 64 per row
            int col = (ci & 7) << 3;
            const __bf16* ga = xb + (size_t)(arow0 + row) * DIM + kk + col;
            const __bf16* gb = xb + (size_t)(brow0 + row) * DIM + kk + col;
            __bf16* la = As + (size_t)(it * 256 + ldsbase) * 8;
            __bf16* lb = Bs + (size_t)(it * 256 + ldsbase) * 8;
            __builtin_amdgcn_global_load_lds(
                (const __attribute__((address_space(1))) void*)ga,
                (__attribute__((address_space(3))) void*)la, 16, 0, 0);
            __builtin_amdgcn_global_load_lds(
                (const __attribute__((address_space(1))) void*)gb,
                (__attribute__((address_space(3))) void*)lb, 16, 0, 0);
        }
        __syncthreads();   // compiler drains vmcnt before s_barrier

#pragma unroll
        for (int k2 = 0; k2 < 2; ++k2) {
            bf16x8 af[4], bfr[4];
#pragma unroll
            for (int m = 0; m < 4; ++m)
                af[m] = *(const bf16x8*)&As[(wr * 64 + m * 16 + lr) * BK + k2 * 32 + lk * 8];
#pragma unroll
            for (int n = 0; n < 4; ++n)
                bfr[n] = *(const bf16x8*)&Bs[(wc * 64 + n * 16 + lr) * BK + k2 * 32 + lk * 8];
#pragma unroll
            for (int m = 0; m < 4; ++m)
#pragma unroll
                for (int n = 0; n < 4; ++n)
                    acc[m][n] = __builtin_amdgcn_mfma_f32_16x16x32_bf16(
                        af[m], bfr[n], acc[m][n], 0, 0, 0);
        }
        __syncthreads();
    }

    // ---- epilogue: fused argmax ----
    // C/D layout (verified m89): col = lane&15, row = (lane>>4)*4 + reg

    // ROW VIEW: rows of bm-block get candidates from bn-block columns
#pragma unroll
    for (int m = 0; m < 4; ++m) {
#pragma unroll
        for (int j = 0; j < 4; ++j) {
            int grow = arow0 + wr * 64 + m * 16 + lk * 4 + j;
            float v = -3.0e38f; int c = 0x7FFFFFFF;
#pragma unroll
            for (int n = 0; n < 4; ++n) {
                int gcol = brow0 + wc * 64 + n * 16 + lr;
                float val = acc[m][n][j];
                if (gcol == grow) val = -1.0f;       // diagonal mask, exact ref semantics
                if (val > v || (val == v && gcol < c)) { v = val; c = gcol; }
            }
#pragma unroll
            for (int s = 1; s < 16; s <<= 1) {       // reduce across the 16-lane col group
                float ov = __shfl_xor(v, s, 64);
                int   oc = __shfl_xor(c, s, 64);
                if (ov > v || (ov == v && oc < c)) { v = ov; c = oc; }
            }
            if (lr == 0) {
                unsigned long long p = ((unsigned long long)ford(v) << 32)
                                     | (unsigned)(0xFFFFFFFFu - (unsigned)c);
                atomicMax(best + grow, p);
            }
        }
    }

    // COL VIEW (symmetry): rows of bn-block get candidates from bm-block rows
#pragma unroll
    for (int n = 0; n < 4; ++n) {
        int gcol = brow0 + wc * 64 + n * 16 + lr;
        float v = -3.0e38f; int c = 0x7FFFFFFF;
#pragma unroll
        for (int m = 0; m < 4; ++m) {
#pragma unroll
            for (int j = 0; j < 4; ++j) {
                int grow = arow0 + wr * 64 + m * 16 + lk * 4 + j;
                float val = acc[m][n][j];
                if (grow == gcol) val = -1.0f;
                if (val > v || (val == v && grow < c)) { v = val; c = grow; }
            }
        }
#pragma unroll
        for (int s = 16; s < 64; s <<= 1) {          // reduce across the 4 row-groups
            float ov = __shfl_xor(v, s, 64);
            int   oc = __shfl_xor(c, s, 64);
            if (ov > v || (ov == v && oc < c)) { v = ov; c = oc; }
        }
        if (lk == 0) {
            unsigned long long p = ((unsigned long long)ford(v) << 32)
                                 | (unsigned)(0xFFFFFFFFu - (unsigned)c);
            atomicMax(best + gcol, p);
        }
    }
}

// =====================================================================
// Kernel 3: per-row fp32 loss term: log(||x_r - x_I + 1e-6||_2 + 1e-8)
// one wave per row, float4 loads, butterfly reduce (deterministic)
// =====================================================================
__global__ void k_rowloss(const float* __restrict__ x,
                          const unsigned long long* __restrict__ best,
                          float* __restrict__ rowloss) {
    int wave = (int)threadIdx.x >> 6, lane = (int)threadIdx.x & 63;
    int r = (int)blockIdx.x * 4 + wave;
    unsigned long long p = best[r];
    int nb = (int)(0xFFFFFFFFu - (unsigned)(p & 0xFFFFFFFFull));
    const float4* xr = (const float4*)(x + (size_t)r  * DIM);
    const float4* xn = (const float4*)(x + (size_t)nb * DIM);
    float s = 0.f;
#pragma unroll
    for (int i = 0; i < 2; ++i) {
        float4 a = xr[lane * 2 + i];
        float4 b = xn[lane * 2 + i];
        float d0 = a.x - b.x + 1e-6f;
        float d1 = a.y - b.y + 1e-6f;
        float d2 = a.z - b.z + 1e-6f;
        float d3 = a.w - b.w + 1e-6f;
        s = fmaf(d0, d0, s); s = fmaf(d1, d1, s);
        s = fmaf(d2, d2, s); s = fmaf(d3, d3, s);
    }
#pragma unroll
    for (int m = 1; m < 64; m <<= 1) s += __shfl_xor(s, m, 64);
    if (lane == 0) rowloss[r] = logf(sqrtf(s) + 1e-8f);
}

// =====================================================================
// Kernel 4: deterministic single-block reduction -> scalar output
// =====================================================================
__global__ void k_reduce(const float* __restrict__ rowloss, float* __restrict__ out) {
    __shared__ float sm[256];
    float s = 0.f;
    for (int i = (int)threadIdx.x; i < N_PTS; i += 256) s += rowloss[i];
    sm[threadIdx.x] = s;
    __syncthreads();
    for (int st = 128; st > 0; st >>= 1) {
        if ((int)threadIdx.x < st) sm[threadIdx.x] += sm[threadIdx.x + st];
        __syncthreads();
    }
    if (threadIdx.x == 0) out[0] = -0.1f * sm[0] / (float)N_PTS;
}

extern "C" void kernel_launch(void* const* d_in, const int* in_sizes, int n_in,
                              void* d_out, int out_size, void* d_ws, size_t ws_size,
                              hipStream_t stream) {
    const float* x = (const float*)d_in[0];
    float* out = (float*)d_out;
    char* ws = (char*)d_ws;

    // ws layout: [bf16 X: 16 MB][best u64[N]: 128 KB][rowloss f32[N]: 64 KB]
    __bf16* xb = (__bf16*)ws;
    unsigned long long* best = (unsigned long long*)(ws + (size_t)N_PTS * DIM * 2);
    float* rowloss = (float*)(ws + (size_t)N_PTS * DIM * 2 + (size_t)N_PTS * 8);

    k_convert<<<dim3(4096), dim3(256), 0, stream>>>(x, xb, best);
    k_gemm_argmax<<<dim3(NTRI), dim3(256), 0, stream>>>(xb, best);
    k_rowloss<<<dim3(N_PTS / 4), dim3(256), 0, stream>>>(x, best, rowloss);
    k_reduce<<<dim3(1), dim3(256), 0, stream>>>(rowloss, out);
}